// Round 2
// baseline (2923.088 us; speedup 1.0000x reference)
//
#include <hip/hip_runtime.h>
#include <hip/hip_fp16.h>

typedef _Float16 f16;
typedef _Float16 f16x2 __attribute__((ext_vector_type(2)));
typedef _Float16 f16x4v __attribute__((ext_vector_type(4)));
typedef _Float16 f16x8 __attribute__((ext_vector_type(8)));
typedef float f32x4 __attribute__((ext_vector_type(4)));

// Combined projection: rows 0..511 = Wq (8 heads x 64), 512..1023 = Wk,
// 1024..1055 = Ww (V), 1056..1311 = Wb (output). Padded to 1344 rows.
#define WC_ROWS 1312
#define WC_PAD 1344

// ---------------- prep: combined weight matrix (f16) + bias (f32) ----------------
__global__ void prep_weights(const float* __restrict__ Wq, const float* __restrict__ bq,
                             const float* __restrict__ Wk, const float* __restrict__ bk,
                             const float* __restrict__ Ww, const float* __restrict__ bw,
                             const float* __restrict__ Wb, const float* __restrict__ bb,
                             f16* __restrict__ Wc, float* __restrict__ bias) {
    int id = blockIdx.x * 256 + threadIdx.x;   // WC_PAD*256 threads
    int j = id >> 8, k = id & 255;
    if (j >= WC_PAD) return;
    float v;
    if (j < 512)       v = Wq[j*256 + k];          // Wq flat [8,64,256]: row h*64+d == j
    else if (j < 1024) v = Wk[(j-512)*256 + k];
    else if (j < 1056) v = Ww[(j-1024)*256 + k];
    else if (j < 1312) v = Wb[(j-1056)*256 + k];
    else               v = 0.f;
    Wc[j*256 + k] = (f16)v;
    if (k == 0) {
        float b;
        if (j < 512)       b = bq[j];
        else if (j < 1024) b = bk[j-512];
        else if (j < 1056) b = bw[j-1024];
        else if (j < 1312) b = bb[j-1056];
        else               b = 0.f;
        bias[j] = b;
    }
}

// ---------------- prep: features fp32 -> f16, zero-pad rows >= n ----------------
__global__ void conv_feat(const float* __restrict__ F, f16* __restrict__ Fh,
                          int n, long total) {
    long id = (long)blockIdx.x * 256 + threadIdx.x;
    long base = id * 4;
    if (base >= total) return;
    long row = base >> 8;
    float4 v = make_float4(0.f, 0.f, 0.f, 0.f);
    if (row < n) v = *(const float4*)(F + base);
    f16x4v o = { (f16)v.x, (f16)v.y, (f16)v.z, (f16)v.w };
    *(f16x4v*)(Fh + base) = o;
}

// ---------------- prep: CSR row starts (edges sorted by src; every row non-empty) --
__global__ void build_rows(const int* __restrict__ src, int E, int n, int* __restrict__ rs) {
    int e = blockIdx.x * 256 + threadIdx.x;
    if (e == 0) rs[n] = E;
    if (e < E) {
        if (e == 0 || src[e] != src[e-1]) rs[src[e]] = e;
    }
}

// ---------------- fused projection GEMM ----------------
// C[m][g] = sum_k Fh[m][k] * Wc[g][k] + bias[g];  scatter by g-region.
// Tile 128x64, BK=32, 4 waves (2x2), mfma_f32_16x16x32_f16.
// Grid: x = N-blocks (21) fastest so the A-panel is L2-reused; B (688KB) stays L2-resident.
__device__ __forceinline__ int swz_slot(int row, int c) {
    // 16B-slot swizzle: 2-way (free) LDS bank pattern for stride-64B b128 frag reads
    return row * 4 + (c ^ (row & 3) ^ ((row >> 2) & 3));
}

__launch_bounds__(256)
__global__ void gemm_fused(const f16* __restrict__ A, const f16* __restrict__ Wc,
                           const float* __restrict__ bias,
                           f16* __restrict__ Qb, f16* __restrict__ Kb, f16* __restrict__ Vb,
                           float* __restrict__ Out, int n) {
    __shared__ uint4 As4[512];   // 128 rows x 32 k (f16) = 8KB
    __shared__ uint4 Bs4[256];   // 64 rows x 32 k = 4KB
    int t = threadIdx.x;
    int lane = t & 63, w = t >> 6;
    int wm = w >> 1, wn = w & 1;
    long m0 = (long)blockIdx.y * 128;
    int n0 = blockIdx.x * 64;

    f32x4 acc[4][2];
    #pragma unroll
    for (int i = 0; i < 4; i++)
        #pragma unroll
        for (int j = 0; j < 2; j++)
            acc[i][j] = (f32x4){0.f, 0.f, 0.f, 0.f};

    int lrow = t >> 2, lc = t & 3;
    const uint4* Ag0 = (const uint4*)(A + (m0 + lrow) * 256 + lc * 8);
    const uint4* Ag1 = (const uint4*)(A + (m0 + 64 + lrow) * 256 + lc * 8);
    const uint4* Bg  = (const uint4*)(Wc + (long)(n0 + lrow) * 256 + lc * 8);
    int ws0 = swz_slot(lrow, lc);
    int ws1 = swz_slot(lrow + 64, lc);
    int csw = (lane >> 4) ^ (lane & 3) ^ ((lane >> 2) & 3);
    int arow = wm * 64 + (lane & 15);
    int brow = wn * 32 + (lane & 15);

    uint4 ra0 = Ag0[0], ra1 = Ag1[0], rb = Bg[0];
    for (int kt = 0; kt < 8; ++kt) {
        if (kt) __syncthreads();
        As4[ws0] = ra0;
        As4[ws1] = ra1;
        Bs4[ws0] = rb;
        __syncthreads();
        if (kt < 7) {            // prefetch next K-slice (row stride 32 uint4, k step 4)
            ra0 = Ag0[(kt + 1) * 4];
            ra1 = Ag1[(kt + 1) * 4];
            rb  = Bg[(kt + 1) * 4];
        }
        f16x8 af[4], bf[2];
        const f16x8* Ap = (const f16x8*)As4;
        const f16x8* Bp = (const f16x8*)Bs4;
        #pragma unroll
        for (int i = 0; i < 4; i++) af[i] = Ap[(arow + i * 16) * 4 + csw];
        #pragma unroll
        for (int j = 0; j < 2; j++) bf[j] = Bp[(brow + j * 16) * 4 + csw];
        #pragma unroll
        for (int i = 0; i < 4; i++)
            #pragma unroll
            for (int j = 0; j < 2; j++)
                acc[i][j] = __builtin_amdgcn_mfma_f32_16x16x32_f16(af[i], bf[j], acc[i][j], 0, 0, 0);
    }

    // epilogue: C row = (lane>>4)*4 + reg, col = lane&15  [guide §3, m89-verified]
    #pragma unroll
    for (int i = 0; i < 4; i++) {
        long gmb = m0 + wm * 64 + i * 16 + (lane >> 4) * 4;
        #pragma unroll
        for (int j = 0; j < 2; j++) {
            int gn = n0 + wn * 32 + j * 16 + (lane & 15);
            float bv = bias[gn];
            #pragma unroll
            for (int r = 0; r < 4; r++) {
                long gm = gmb + r;
                if (gm >= n) continue;
                float v = acc[i][j][r] + bv;
                if (gn < 512)       Qb[gm * 512 + gn] = (f16)v;
                else if (gn < 1024) Kb[gm * 512 + (gn - 512)] = (f16)v;
                else if (gn < 1056) Vb[gm * 32 + (gn - 1024)] = (f16)v;
                else if (gn < 1312) Out[gm * 256 + (gn - 1056)] = v;
            }
        }
    }
}

// ---------------- edge attention: one wave per row, flash-style, MFMA aggregation --
__device__ __forceinline__ float fd2(unsigned a, unsigned b, float c) {
#if defined(__has_builtin)
#if __has_builtin(__builtin_amdgcn_fdot2)
    return __builtin_amdgcn_fdot2(__builtin_bit_cast(f16x2, a), __builtin_bit_cast(f16x2, b), c, false);
#else
    f16x2 x = __builtin_bit_cast(f16x2, a), y = __builtin_bit_cast(f16x2, b);
    return c + (float)x[0] * (float)y[0] + (float)x[1] * (float)y[1];
#endif
#else
    f16x2 x = __builtin_bit_cast(f16x2, a), y = __builtin_bit_cast(f16x2, b);
    return c + (float)x[0] * (float)y[0] + (float)x[1] * (float)y[1];
#endif
}

// Aggregation per tile: out[16h x 32d] = P[16h x 64e] @ V[64e x 32d] via 4 MFMAs.
// P staged in wave-private LDS (XOR-swizzled, conflict-free b128 A-frag reads);
// V gathered from global directly in B-fragment layout (32 indep scalar loads).
// No __syncthreads: all LDS regions are per-wave.
__launch_bounds__(256, 4)
__global__ void edge_attn(const int* __restrict__ rs, const int* __restrict__ dstA,
                          const f16* __restrict__ Qb, const f16* __restrict__ Kb,
                          const f16* __restrict__ Vb, float* __restrict__ Out, int n) {
    __shared__ __align__(16) f16 P_lds[4][16][64];  // [wave][head(8 used)][edge], e^(h<<3) swizzle
    __shared__ int dS[4][64];                        // dst per edge slot
    int w = threadIdx.x >> 6, lane = threadIdx.x & 63;
    int row = blockIdx.x * 4 + w;
    if (row >= n) return;
    int e0 = rs[row], deg = rs[row + 1] - e0;
    const uint4* qp = (const uint4*)(Qb + (size_t)row * 512);
    float m[8], l[8];
    #pragma unroll
    for (int h = 0; h < 8; h++) { m[h] = -1e30f; l[h] = 0.f; }
    f32x4 acc[2] = {(f32x4){0.f,0.f,0.f,0.f}, (f32x4){0.f,0.f,0.f,0.f}};
    int hsel = (lane >> 4) & 1;     // D rows: h = (lane>>4)*4 + r; lanes<32 hold h 0..7
    int ec0 = (lane >> 4) * 8;      // k-chunk base (edge index within tile)
    int h_a = lane & 15;            // A-frag row (head)

    for (int base = 0; base < deg; base += 64) {
        int nE = min(64, deg - base);
        bool act = lane < nE;
        int d = dstA[e0 + base + (act ? lane : 0)];
        dS[w][lane] = d;
        const uint4* kp = (const uint4*)(Kb + (size_t)d * 512);
        // 8-head scores: 64-dim f16 dot per head via v_dot2
        float s[8];
        #pragma unroll
        for (int h = 0; h < 8; h++) {
            float a = 0.f;
            #pragma unroll
            for (int c = 0; c < 8; c++) {
                uint4 kv = kp[h * 8 + c], qv = qp[h * 8 + c];
                a = fd2(qv.x, kv.x, a);
                a = fd2(qv.y, kv.y, a);
                a = fd2(qv.z, kv.z, a);
                a = fd2(qv.w, kv.w, a);
            }
            s[h] = a;
        }
        // online softmax: butterfly max/sum; stash unnormalized p (f16) into P_lds
        float sc[8];
        #pragma unroll
        for (int h = 0; h < 8; h++) {
            float sv = act ? s[h] : -1e30f;
            #pragma unroll
            for (int off = 1; off < 64; off <<= 1) sv = fmaxf(sv, __shfl_xor(sv, off));
            float nm = fmaxf(m[h], sv);
            sc[h] = __expf(m[h] - nm);
            float p = act ? __expf(s[h] - nm) : 0.f;
            P_lds[w][h][lane ^ (h << 3)] = (f16)p;
            #pragma unroll
            for (int off = 1; off < 64; off <<= 1) p += __shfl_xor(p, off);
            l[h] = l[h] * sc[h] + p;
            m[h] = nm;
        }
        // rescale accumulator (head = hsel*4 + r; lanes>=32 hold unused rows)
        #pragma unroll
        for (int r = 0; r < 4; r++) {
            float f = hsel ? sc[r + 4] : sc[r];
            acc[0][r] *= f;
            acc[1][r] *= f;
        }
        // A-fragments: P[h][k] , k = ks*32 + ec0 + j  (XOR-decoded contiguous b128)
        f16x8 a0 = *(const f16x8*)&P_lds[w][h_a][(ec0)      ^ ((h_a & 7) << 3)];
        f16x8 a1 = *(const f16x8*)&P_lds[w][h_a][(32 + ec0) ^ ((h_a & 7) << 3)];
        // B-fragments: V[e][dim], e = ks*32 + ec0 + j, dim = nh*16 + (lane&15)
        f16x8 bf0a, bf0b, bf1a, bf1b;
        #pragma unroll
        for (int j = 0; j < 8; j++) {
            int dd0 = dS[w][ec0 + j];
            int dd1 = dS[w][32 + ec0 + j];
            const f16* vp0 = Vb + (size_t)dd0 * 32 + (lane & 15);
            const f16* vp1 = Vb + (size_t)dd1 * 32 + (lane & 15);
            bf0a[j] = vp0[0];
            bf0b[j] = vp0[16];
            bf1a[j] = vp1[0];
            bf1b[j] = vp1[16];
        }
        acc[0] = __builtin_amdgcn_mfma_f32_16x16x32_f16(a0, bf0a, acc[0], 0, 0, 0);
        acc[0] = __builtin_amdgcn_mfma_f32_16x16x32_f16(a1, bf1a, acc[0], 0, 0, 0);
        acc[1] = __builtin_amdgcn_mfma_f32_16x16x32_f16(a0, bf0b, acc[1], 0, 0, 0);
        acc[1] = __builtin_amdgcn_mfma_f32_16x16x32_f16(a1, bf1b, acc[1], 0, 0, 0);
    }
    // epilogue: D row = (lane>>4)*4 + r = head, col = lane&15; out dim = h*32 + nh*16 + col
    if (lane < 32) {
        float* op = Out + (size_t)row * 256 + (lane & 15);
        #pragma unroll
        for (int r = 0; r < 4; r++) {
            int h = hsel * 4 + r;
            float dn = hsel ? l[r + 4] : l[r];
            float inv = 1.f / dn;
            op[h * 32]      += acc[0][r] * inv;
            op[h * 32 + 16] += acc[1][r] * inv;
        }
    }
}

// ---------------- launch ----------------
extern "C" void kernel_launch(void* const* d_in, const int* in_sizes, int n_in,
                              void* d_out, int out_size, void* d_ws, size_t ws_size,
                              hipStream_t stream) {
    const float* F  = (const float*)d_in[0];
    const int*   ei = (const int*)d_in[1];
    const float* Wq = (const float*)d_in[2];
    const float* bq = (const float*)d_in[3];
    const float* Wk = (const float*)d_in[4];
    const float* bk = (const float*)d_in[5];
    const float* Ww = (const float*)d_in[6];
    const float* bw = (const float*)d_in[7];
    const float* Wb = (const float*)d_in[8];
    const float* bb = (const float*)d_in[9];
    int n = in_sizes[0] / 256;       // 50000
    int E = in_sizes[1] / 2;
    const int* srcA = ei;
    const int* dstA = ei + E;
    int n_pad = (n + 127) & ~127;

    // workspace carve-out (~132 MB)
    char* wp = (char*)d_ws;
    auto alloc = [&](size_t bytes) { void* p = wp; wp += (bytes + 255) & ~255ull; return p; };
    f16*   Fh   = (f16*)alloc((size_t)n_pad * 256 * 2);
    f16*   Wc   = (f16*)alloc((size_t)WC_PAD * 256 * 2);
    float* bias = (float*)alloc((size_t)WC_PAD * 4);
    f16*   Qb   = (f16*)alloc((size_t)n * 512 * 2);
    f16*   Kb   = (f16*)alloc((size_t)n * 512 * 2);
    f16*   Vb   = (f16*)alloc((size_t)n * 32 * 2);
    int*   rs   = (int*)alloc((size_t)(n + 1) * 4);
    float* Out  = (float*)d_out;

    prep_weights<<<WC_PAD, 256, 0, stream>>>(Wq, bq, Wk, bk, Ww, bw, Wb, bb, Wc, bias);
    long totalF = (long)n_pad * 256;
    conv_feat<<<(int)((totalF / 4 + 255) / 256), 256, 0, stream>>>(F, Fh, n, totalF);
    build_rows<<<(E + 255) / 256, 256, 0, stream>>>(srcA, E, n, rs);
    dim3 g(WC_PAD / 64, n_pad / 128);   // N fastest: A-panel L2-reuse, B L2-resident
    gemm_fused<<<g, 256, 0, stream>>>(Fh, Wc, bias, Qb, Kb, Vb, Out, n);
    edge_attn<<<(n + 3) / 4, 256, 0, stream>>>(rs, dstA, Qb, Kb, Vb, Out, n);
}

// Round 3
// 1534.292 us; speedup vs baseline: 1.9052x; 1.9052x over previous
//
#include <hip/hip_runtime.h>
#include <hip/hip_fp16.h>

typedef _Float16 f16;
typedef _Float16 f16x2 __attribute__((ext_vector_type(2)));
typedef _Float16 f16x4v __attribute__((ext_vector_type(4)));
typedef _Float16 f16x8 __attribute__((ext_vector_type(8)));
typedef float f32x4 __attribute__((ext_vector_type(4)));

// Combined projection: rows 0..511 = Wq (8 heads x 64), 512..1023 = Wk,
// 1024..1055 = Ww (V), 1056..1311 = Wb (output). Padded to 1344 rows.
#define WC_ROWS 1312
#define WC_PAD 1344

// ---------------- prep: combined weight matrix (f16) + bias (f32) ----------------
__global__ void prep_weights(const float* __restrict__ Wq, const float* __restrict__ bq,
                             const float* __restrict__ Wk, const float* __restrict__ bk,
                             const float* __restrict__ Ww, const float* __restrict__ bw,
                             const float* __restrict__ Wb, const float* __restrict__ bb,
                             f16* __restrict__ Wc, float* __restrict__ bias) {
    int id = blockIdx.x * 256 + threadIdx.x;   // WC_PAD*256 threads
    int j = id >> 8, k = id & 255;
    if (j >= WC_PAD) return;
    float v;
    if (j < 512)       v = Wq[j*256 + k];          // Wq flat [8,64,256]: row h*64+d == j
    else if (j < 1024) v = Wk[(j-512)*256 + k];
    else if (j < 1056) v = Ww[(j-1024)*256 + k];
    else if (j < 1312) v = Wb[(j-1056)*256 + k];
    else               v = 0.f;
    Wc[j*256 + k] = (f16)v;
    if (k == 0) {
        float b;
        if (j < 512)       b = bq[j];
        else if (j < 1024) b = bk[j-512];
        else if (j < 1056) b = bw[j-1024];
        else if (j < 1312) b = bb[j-1056];
        else               b = 0.f;
        bias[j] = b;
    }
}

// ---------------- prep: features fp32 -> f16, zero-pad rows >= n ----------------
__global__ void conv_feat(const float* __restrict__ F, f16* __restrict__ Fh,
                          int n, long total) {
    long id = (long)blockIdx.x * 256 + threadIdx.x;
    long base = id * 4;
    if (base >= total) return;
    long row = base >> 8;
    float4 v = make_float4(0.f, 0.f, 0.f, 0.f);
    if (row < n) v = *(const float4*)(F + base);
    f16x4v o = { (f16)v.x, (f16)v.y, (f16)v.z, (f16)v.w };
    *(f16x4v*)(Fh + base) = o;
}

// ---------------- prep: CSR row starts (edges sorted by src; every row non-empty) --
__global__ void build_rows(const int* __restrict__ src, int E, int n, int* __restrict__ rs) {
    int e = blockIdx.x * 256 + threadIdx.x;
    if (e == 0) rs[n] = E;
    if (e < E) {
        if (e == 0 || src[e] != src[e-1]) rs[src[e]] = e;
    }
}

// ---------------- fused projection GEMM ----------------
// C[m][g] = sum_k Fh[m][k] * Wc[g][k] + bias[g];  scatter by g-region.
// Tile 128x64, BK=32, 4 waves (2x2), mfma_f32_16x16x32_f16.
// Grid: x = N-blocks (21) fastest so the A-panel is L2-reused; B (688KB) stays L2-resident.
__device__ __forceinline__ int swz_slot(int row, int c) {
    // 16B-slot swizzle: 2-way (free) LDS bank pattern for stride-64B b128 frag reads
    return row * 4 + (c ^ (row & 3) ^ ((row >> 2) & 3));
}

__launch_bounds__(256)
__global__ void gemm_fused(const f16* __restrict__ A, const f16* __restrict__ Wc,
                           const float* __restrict__ bias,
                           f16* __restrict__ Qb, f16* __restrict__ Kb, f16* __restrict__ Vb,
                           float* __restrict__ Out, int n) {
    __shared__ uint4 As4[512];   // 128 rows x 32 k (f16) = 8KB
    __shared__ uint4 Bs4[256];   // 64 rows x 32 k = 4KB
    int t = threadIdx.x;
    int lane = t & 63, w = t >> 6;
    int wm = w >> 1, wn = w & 1;
    long m0 = (long)blockIdx.y * 128;
    int n0 = blockIdx.x * 64;

    f32x4 acc[4][2];
    #pragma unroll
    for (int i = 0; i < 4; i++)
        #pragma unroll
        for (int j = 0; j < 2; j++)
            acc[i][j] = (f32x4){0.f, 0.f, 0.f, 0.f};

    int lrow = t >> 2, lc = t & 3;
    const uint4* Ag0 = (const uint4*)(A + (m0 + lrow) * 256 + lc * 8);
    const uint4* Ag1 = (const uint4*)(A + (m0 + 64 + lrow) * 256 + lc * 8);
    const uint4* Bg  = (const uint4*)(Wc + (long)(n0 + lrow) * 256 + lc * 8);
    int ws0 = swz_slot(lrow, lc);
    int ws1 = swz_slot(lrow + 64, lc);
    int csw = (lane >> 4) ^ (lane & 3) ^ ((lane >> 2) & 3);
    int arow = wm * 64 + (lane & 15);
    int brow = wn * 32 + (lane & 15);

    uint4 ra0 = Ag0[0], ra1 = Ag1[0], rb = Bg[0];
    for (int kt = 0; kt < 8; ++kt) {
        if (kt) __syncthreads();
        As4[ws0] = ra0;
        As4[ws1] = ra1;
        Bs4[ws0] = rb;
        __syncthreads();
        if (kt < 7) {            // prefetch next K-slice (row stride 32 uint4, k step 4)
            ra0 = Ag0[(kt + 1) * 4];
            ra1 = Ag1[(kt + 1) * 4];
            rb  = Bg[(kt + 1) * 4];
        }
        f16x8 af[4], bf[2];
        const f16x8* Ap = (const f16x8*)As4;
        const f16x8* Bp = (const f16x8*)Bs4;
        #pragma unroll
        for (int i = 0; i < 4; i++) af[i] = Ap[(arow + i * 16) * 4 + csw];
        #pragma unroll
        for (int j = 0; j < 2; j++) bf[j] = Bp[(brow + j * 16) * 4 + csw];
        #pragma unroll
        for (int i = 0; i < 4; i++)
            #pragma unroll
            for (int j = 0; j < 2; j++)
                acc[i][j] = __builtin_amdgcn_mfma_f32_16x16x32_f16(af[i], bf[j], acc[i][j], 0, 0, 0);
    }

    // epilogue: C row = (lane>>4)*4 + reg, col = lane&15  [guide §3, m89-verified]
    #pragma unroll
    for (int i = 0; i < 4; i++) {
        long gmb = m0 + wm * 64 + i * 16 + (lane >> 4) * 4;
        #pragma unroll
        for (int j = 0; j < 2; j++) {
            int gn = n0 + wn * 32 + j * 16 + (lane & 15);
            float bv = bias[gn];
            #pragma unroll
            for (int r = 0; r < 4; r++) {
                long gm = gmb + r;
                if (gm >= n) continue;
                float v = acc[i][j][r] + bv;
                if (gn < 512)       Qb[gm * 512 + gn] = (f16)v;
                else if (gn < 1024) Kb[gm * 512 + (gn - 512)] = (f16)v;
                else if (gn < 1056) Vb[gm * 32 + (gn - 1024)] = (f16)v;
                else if (gn < 1312) Out[gm * 256 + (gn - 1056)] = v;
            }
        }
    }
}

// ---------------- edge attention: one wave per row, flash-style, MFMA aggregation --
__device__ __forceinline__ float fd2(unsigned a, unsigned b, float c) {
#if defined(__has_builtin)
#if __has_builtin(__builtin_amdgcn_fdot2)
    return __builtin_amdgcn_fdot2(__builtin_bit_cast(f16x2, a), __builtin_bit_cast(f16x2, b), c, false);
#else
    f16x2 x = __builtin_bit_cast(f16x2, a), y = __builtin_bit_cast(f16x2, b);
    return c + (float)x[0] * (float)y[0] + (float)x[1] * (float)y[1];
#endif
#else
    f16x2 x = __builtin_bit_cast(f16x2, a), y = __builtin_bit_cast(f16x2, b);
    return c + (float)x[0] * (float)y[0] + (float)x[1] * (float)y[1];
#endif
}

// Aggregation per tile: out[16h x 32d] = P[16h x 64e] @ V[64e x 32d] via 4 MFMAs.
// P staged in wave-private LDS (XOR-swizzled, conflict-free b128 A-frag reads);
// V gathered from global directly in B-fragment layout (32 indep scalar loads).
// No __syncthreads: all LDS regions are per-wave.
// NOTE: no min-waves clamp in launch_bounds — (256,4) forced VGPR=64 and the
// whole working set spilled to scratch (WRITE_SIZE 190MB -> 3GB, dur 2.5x).
__launch_bounds__(256)
__global__ void edge_attn(const int* __restrict__ rs, const int* __restrict__ dstA,
                          const f16* __restrict__ Qb, const f16* __restrict__ Kb,
                          const f16* __restrict__ Vb, float* __restrict__ Out, int n) {
    __shared__ __align__(16) f16 P_lds[4][16][64];  // [wave][head(8 used)][edge], e^(h<<3) swizzle
    __shared__ int dS[4][64];                        // dst per edge slot
    int w = threadIdx.x >> 6, lane = threadIdx.x & 63;
    int row = blockIdx.x * 4 + w;
    if (row >= n) return;
    int e0 = rs[row], deg = rs[row + 1] - e0;
    const uint4* qp = (const uint4*)(Qb + (size_t)row * 512);
    float m[8], l[8];
    #pragma unroll
    for (int h = 0; h < 8; h++) { m[h] = -1e30f; l[h] = 0.f; }
    f32x4 acc[2] = {(f32x4){0.f,0.f,0.f,0.f}, (f32x4){0.f,0.f,0.f,0.f}};
    int hsel = (lane >> 4) & 1;     // D rows: h = (lane>>4)*4 + r; lanes<32 hold h 0..7
    int ec0 = (lane >> 4) * 8;      // k-chunk base (edge index within tile)
    int h_a = lane & 15;            // A-frag row (head)

    for (int base = 0; base < deg; base += 64) {
        int nE = min(64, deg - base);
        bool act = lane < nE;
        int d = dstA[e0 + base + (act ? lane : 0)];
        dS[w][lane] = d;
        const uint4* kp = (const uint4*)(Kb + (size_t)d * 512);
        // 8-head scores: 64-dim f16 dot per head via v_dot2
        float s[8];
        #pragma unroll
        for (int h = 0; h < 8; h++) {
            float a = 0.f;
            #pragma unroll
            for (int c = 0; c < 8; c++) {
                uint4 kv = kp[h * 8 + c], qv = qp[h * 8 + c];
                a = fd2(qv.x, kv.x, a);
                a = fd2(qv.y, kv.y, a);
                a = fd2(qv.z, kv.z, a);
                a = fd2(qv.w, kv.w, a);
            }
            s[h] = a;
        }
        // online softmax: butterfly max/sum; stash unnormalized p (f16) into P_lds
        float sc[8];
        #pragma unroll
        for (int h = 0; h < 8; h++) {
            float sv = act ? s[h] : -1e30f;
            #pragma unroll
            for (int off = 1; off < 64; off <<= 1) sv = fmaxf(sv, __shfl_xor(sv, off));
            float nm = fmaxf(m[h], sv);
            sc[h] = __expf(m[h] - nm);
            float p = act ? __expf(s[h] - nm) : 0.f;
            P_lds[w][h][lane ^ (h << 3)] = (f16)p;
            #pragma unroll
            for (int off = 1; off < 64; off <<= 1) p += __shfl_xor(p, off);
            l[h] = l[h] * sc[h] + p;
            m[h] = nm;
        }
        // rescale accumulator (head = hsel*4 + r; lanes>=32 hold unused rows)
        #pragma unroll
        for (int r = 0; r < 4; r++) {
            float f = hsel ? sc[r + 4] : sc[r];
            acc[0][r] *= f;
            acc[1][r] *= f;
        }
        // A-fragments: P[h][k] , k = ks*32 + ec0 + j  (XOR-decoded contiguous b128)
        f16x8 a0 = *(const f16x8*)&P_lds[w][h_a][(ec0)      ^ ((h_a & 7) << 3)];
        f16x8 a1 = *(const f16x8*)&P_lds[w][h_a][(32 + ec0) ^ ((h_a & 7) << 3)];
        // B-fragments: V[e][dim], e = ks*32 + ec0 + j, dim = nh*16 + (lane&15)
        f16x8 bf0a, bf0b, bf1a, bf1b;
        #pragma unroll
        for (int j = 0; j < 8; j++) {
            int dd0 = dS[w][ec0 + j];
            int dd1 = dS[w][32 + ec0 + j];
            const f16* vp0 = Vb + (size_t)dd0 * 32 + (lane & 15);
            const f16* vp1 = Vb + (size_t)dd1 * 32 + (lane & 15);
            bf0a[j] = vp0[0];
            bf0b[j] = vp0[16];
            bf1a[j] = vp1[0];
            bf1b[j] = vp1[16];
        }
        acc[0] = __builtin_amdgcn_mfma_f32_16x16x32_f16(a0, bf0a, acc[0], 0, 0, 0);
        acc[0] = __builtin_amdgcn_mfma_f32_16x16x32_f16(a1, bf1a, acc[0], 0, 0, 0);
        acc[1] = __builtin_amdgcn_mfma_f32_16x16x32_f16(a0, bf0b, acc[1], 0, 0, 0);
        acc[1] = __builtin_amdgcn_mfma_f32_16x16x32_f16(a1, bf1b, acc[1], 0, 0, 0);
    }
    // epilogue: D row = (lane>>4)*4 + r = head, col = lane&15; out dim = h*32 + nh*16 + col
    if (lane < 32) {
        float* op = Out + (size_t)row * 256 + (lane & 15);
        #pragma unroll
        for (int r = 0; r < 4; r++) {
            int h = hsel * 4 + r;
            float dn = hsel ? l[r + 4] : l[r];
            float inv = 1.f / dn;
            op[h * 32]      += acc[0][r] * inv;
            op[h * 32 + 16] += acc[1][r] * inv;
        }
    }
}

// ---------------- launch ----------------
extern "C" void kernel_launch(void* const* d_in, const int* in_sizes, int n_in,
                              void* d_out, int out_size, void* d_ws, size_t ws_size,
                              hipStream_t stream) {
    const float* F  = (const float*)d_in[0];
    const int*   ei = (const int*)d_in[1];
    const float* Wq = (const float*)d_in[2];
    const float* bq = (const float*)d_in[3];
    const float* Wk = (const float*)d_in[4];
    const float* bk = (const float*)d_in[5];
    const float* Ww = (const float*)d_in[6];
    const float* bw = (const float*)d_in[7];
    const float* Wb = (const float*)d_in[8];
    const float* bb = (const float*)d_in[9];
    int n = in_sizes[0] / 256;       // 50000
    int E = in_sizes[1] / 2;
    const int* srcA = ei;
    const int* dstA = ei + E;
    int n_pad = (n + 127) & ~127;

    // workspace carve-out (~132 MB)
    char* wp = (char*)d_ws;
    auto alloc = [&](size_t bytes) { void* p = wp; wp += (bytes + 255) & ~255ull; return p; };
    f16*   Fh   = (f16*)alloc((size_t)n_pad * 256 * 2);
    f16*   Wc   = (f16*)alloc((size_t)WC_PAD * 256 * 2);
    float* bias = (float*)alloc((size_t)WC_PAD * 4);
    f16*   Qb   = (f16*)alloc((size_t)n * 512 * 2);
    f16*   Kb   = (f16*)alloc((size_t)n * 512 * 2);
    f16*   Vb   = (f16*)alloc((size_t)n * 32 * 2);
    int*   rs   = (int*)alloc((size_t)(n + 1) * 4);
    float* Out  = (float*)d_out;

    prep_weights<<<WC_PAD, 256, 0, stream>>>(Wq, bq, Wk, bk, Ww, bw, Wb, bb, Wc, bias);
    long totalF = (long)n_pad * 256;
    conv_feat<<<(int)((totalF / 4 + 255) / 256), 256, 0, stream>>>(F, Fh, n, totalF);
    build_rows<<<(E + 255) / 256, 256, 0, stream>>>(srcA, E, n, rs);
    dim3 g(WC_PAD / 64, n_pad / 128);   // N fastest: A-panel L2-reuse, B L2-resident
    gemm_fused<<<g, 256, 0, stream>>>(Fh, Wc, bias, Qb, Kb, Vb, Out, n);
    edge_attn<<<(n + 3) / 4, 256, 0, stream>>>(rs, dstA, Qb, Kb, Vb, Out, n);
}

// Round 4
// 576.931 us; speedup vs baseline: 5.0666x; 2.6594x over previous
//
#include <hip/hip_runtime.h>
#include <hip/hip_fp16.h>

typedef _Float16 f16;
typedef _Float16 f16x2 __attribute__((ext_vector_type(2)));
typedef _Float16 f16x4v __attribute__((ext_vector_type(4)));
typedef _Float16 f16x8 __attribute__((ext_vector_type(8)));
typedef float f32x4 __attribute__((ext_vector_type(4)));

// Combined projection: rows 0..511 = Wq (8 heads x 64), 512..1023 = Wk,
// 1024..1055 = Ww (V), 1056..1311 = Wb (output). Padded to 1344 rows.
#define WC_ROWS 1312
#define WC_PAD 1344

// ---------------- prep: combined weight matrix (f16) + bias (f32) ----------------
__global__ void prep_weights(const float* __restrict__ Wq, const float* __restrict__ bq,
                             const float* __restrict__ Wk, const float* __restrict__ bk,
                             const float* __restrict__ Ww, const float* __restrict__ bw,
                             const float* __restrict__ Wb, const float* __restrict__ bb,
                             f16* __restrict__ Wc, float* __restrict__ bias) {
    int id = blockIdx.x * 256 + threadIdx.x;   // WC_PAD*256 threads
    int j = id >> 8, k = id & 255;
    if (j >= WC_PAD) return;
    float v;
    if (j < 512)       v = Wq[j*256 + k];          // Wq flat [8,64,256]: row h*64+d == j
    else if (j < 1024) v = Wk[(j-512)*256 + k];
    else if (j < 1056) v = Ww[(j-1024)*256 + k];
    else if (j < 1312) v = Wb[(j-1056)*256 + k];
    else               v = 0.f;
    Wc[j*256 + k] = (f16)v;
    if (k == 0) {
        float b;
        if (j < 512)       b = bq[j];
        else if (j < 1024) b = bk[j-512];
        else if (j < 1056) b = bw[j-1024];
        else if (j < 1312) b = bb[j-1056];
        else               b = 0.f;
        bias[j] = b;
    }
}

// ---------------- prep: features fp32 -> f16, zero-pad rows >= n ----------------
__global__ void conv_feat(const float* __restrict__ F, f16* __restrict__ Fh,
                          int n, long total) {
    long id = (long)blockIdx.x * 256 + threadIdx.x;
    long base = id * 4;
    if (base >= total) return;
    long row = base >> 8;
    float4 v = make_float4(0.f, 0.f, 0.f, 0.f);
    if (row < n) v = *(const float4*)(F + base);
    f16x4v o = { (f16)v.x, (f16)v.y, (f16)v.z, (f16)v.w };
    *(f16x4v*)(Fh + base) = o;
}

// ---------------- prep: CSR row starts (edges sorted by src; every row non-empty) --
__global__ void build_rows(const int* __restrict__ src, int E, int n, int* __restrict__ rs) {
    int e = blockIdx.x * 256 + threadIdx.x;
    if (e == 0) rs[n] = E;
    if (e < E) {
        if (e == 0 || src[e] != src[e-1]) rs[src[e]] = e;
    }
}

// ---------------- fused projection GEMM ----------------
// C[m][g] = sum_k Fh[m][k] * Wc[g][k] + bias[g];  scatter by g-region.
// Tile 128x64, BK=32, 4 waves (2x2), mfma_f32_16x16x32_f16.
__device__ __forceinline__ int swz_slot(int row, int c) {
    return row * 4 + (c ^ (row & 3) ^ ((row >> 2) & 3));
}

__launch_bounds__(256)
__global__ void gemm_fused(const f16* __restrict__ A, const f16* __restrict__ Wc,
                           const float* __restrict__ bias,
                           f16* __restrict__ Qb, f16* __restrict__ Kb, f16* __restrict__ Vb,
                           float* __restrict__ Out, int n) {
    __shared__ uint4 As4[512];   // 128 rows x 32 k (f16) = 8KB
    __shared__ uint4 Bs4[256];   // 64 rows x 32 k = 4KB
    int t = threadIdx.x;
    int lane = t & 63, w = t >> 6;
    int wm = w >> 1, wn = w & 1;
    long m0 = (long)blockIdx.y * 128;
    int n0 = blockIdx.x * 64;

    f32x4 acc[4][2];
    #pragma unroll
    for (int i = 0; i < 4; i++)
        #pragma unroll
        for (int j = 0; j < 2; j++)
            acc[i][j] = (f32x4){0.f, 0.f, 0.f, 0.f};

    int lrow = t >> 2, lc = t & 3;
    const uint4* Ag0 = (const uint4*)(A + (m0 + lrow) * 256 + lc * 8);
    const uint4* Ag1 = (const uint4*)(A + (m0 + 64 + lrow) * 256 + lc * 8);
    const uint4* Bg  = (const uint4*)(Wc + (long)(n0 + lrow) * 256 + lc * 8);
    int ws0 = swz_slot(lrow, lc);
    int ws1 = swz_slot(lrow + 64, lc);
    int csw = (lane >> 4) ^ (lane & 3) ^ ((lane >> 2) & 3);
    int arow = wm * 64 + (lane & 15);
    int brow = wn * 32 + (lane & 15);

    uint4 ra0 = Ag0[0], ra1 = Ag1[0], rb = Bg[0];
    for (int kt = 0; kt < 8; ++kt) {
        if (kt) __syncthreads();
        As4[ws0] = ra0;
        As4[ws1] = ra1;
        Bs4[ws0] = rb;
        __syncthreads();
        if (kt < 7) {
            ra0 = Ag0[(kt + 1) * 4];
            ra1 = Ag1[(kt + 1) * 4];
            rb  = Bg[(kt + 1) * 4];
        }
        f16x8 af[4], bf[2];
        const f16x8* Ap = (const f16x8*)As4;
        const f16x8* Bp = (const f16x8*)Bs4;
        #pragma unroll
        for (int i = 0; i < 4; i++) af[i] = Ap[(arow + i * 16) * 4 + csw];
        #pragma unroll
        for (int j = 0; j < 2; j++) bf[j] = Bp[(brow + j * 16) * 4 + csw];
        #pragma unroll
        for (int i = 0; i < 4; i++)
            #pragma unroll
            for (int j = 0; j < 2; j++)
                acc[i][j] = __builtin_amdgcn_mfma_f32_16x16x32_f16(af[i], bf[j], acc[i][j], 0, 0, 0);
    }

    #pragma unroll
    for (int i = 0; i < 4; i++) {
        long gmb = m0 + wm * 64 + i * 16 + (lane >> 4) * 4;
        #pragma unroll
        for (int j = 0; j < 2; j++) {
            int gn = n0 + wn * 32 + j * 16 + (lane & 15);
            float bv = bias[gn];
            #pragma unroll
            for (int r = 0; r < 4; r++) {
                long gm = gmb + r;
                if (gm >= n) continue;
                float v = acc[i][j][r] + bv;
                if (gn < 512)       Qb[gm * 512 + gn] = (f16)v;
                else if (gn < 1024) Kb[gm * 512 + (gn - 512)] = (f16)v;
                else if (gn < 1056) Vb[gm * 32 + (gn - 1024)] = (f16)v;
                else if (gn < 1312) Out[gm * 256 + (gn - 1056)] = v;
            }
        }
    }
}

// ---------------- f16x2 dot helper ----------------
__device__ __forceinline__ float fd2(unsigned a, unsigned b, float c) {
#if defined(__has_builtin)
#if __has_builtin(__builtin_amdgcn_fdot2)
    return __builtin_amdgcn_fdot2(__builtin_bit_cast(f16x2, a), __builtin_bit_cast(f16x2, b), c, false);
#else
    f16x2 x = __builtin_bit_cast(f16x2, a), y = __builtin_bit_cast(f16x2, b);
    return c + (float)x[0] * (float)y[0] + (float)x[1] * (float)y[1];
#endif
#else
    f16x2 x = __builtin_bit_cast(f16x2, a), y = __builtin_bit_cast(f16x2, b);
    return c + (float)x[0] * (float)y[0] + (float)x[1] * (float)y[1];
#endif
}

// ---------------- phase A: edge-parallel scores ----------------
// 8 lanes per edge (lane = head). Each lane dots 64 dims (128B of Q and K).
// Edges sorted by src -> Q row is L1/L2-hot across consecutive edges; K is the
// fundamental random gather (E x 1KB). Massive TLP hides gather latency.
__launch_bounds__(256)
__global__ void edge_scores(const int* __restrict__ srcA, const int* __restrict__ dstA,
                            const f16* __restrict__ Qb, const f16* __restrict__ Kb,
                            f16* __restrict__ sE, int E) {
    int id = blockIdx.x * 256 + threadIdx.x;
    int e = id >> 3, h = id & 7;
    if (e >= E) return;
    int s = srcA[e], d = dstA[e];
    const uint4* qp = (const uint4*)(Qb + (size_t)s * 512 + h * 64);
    const uint4* kp = (const uint4*)(Kb + (size_t)d * 512 + h * 64);
    float a = 0.f;
    #pragma unroll
    for (int c = 0; c < 8; c++) {
        uint4 qv = qp[c], kv = kp[c];
        a = fd2(qv.x, kv.x, a);
        a = fd2(qv.y, kv.y, a);
        a = fd2(qv.z, kv.z, a);
        a = fd2(qv.w, kv.w, a);
    }
    sE[(size_t)e * 8 + h] = (f16)a;   // [e][h], coalesced wave store
}

// ---------------- phase B: row-parallel softmax + MFMA aggregation ----------------
// Wave per row. Pass 1: per-head max (one butterfly set per row). Pass 2:
// P = exp(s-m) -> LDS (XOR-swizzled); out[16h x 32d] = P @ Vgather via 4 MFMAs;
// denominator l = P @ ones via 2 more MFMAs (lands in acc layout -> no sum shuffles).
__launch_bounds__(256)
__global__ void edge_agg(const int* __restrict__ rs, const int* __restrict__ dstA,
                         const f16* __restrict__ sE, const f16* __restrict__ Vb,
                         float* __restrict__ Out, int n) {
    __shared__ __align__(16) f16 P_lds[4][16][64];
    __shared__ int dS[4][64];
    int w = threadIdx.x >> 6, lane = threadIdx.x & 63;
    int row = blockIdx.x * 4 + w;
    if (row >= n) return;
    int e0 = rs[row], deg = rs[row + 1] - e0;
    {   // zero A-frag rows 8..15 (read by MFMA, results discarded; avoid NaN garbage)
        f16x8 z = {};
        *(f16x8*)&P_lds[w][8 + (lane >> 3)][(lane & 7) * 8] = z;
    }
    // pass 1: global per-head max
    float pm[8];
    #pragma unroll
    for (int h = 0; h < 8; h++) pm[h] = -1e30f;
    for (int base = 0; base < deg; base += 64) {
        bool act = lane < deg - base;
        f16x8 s8 = {};
        if (act) s8 = *(const f16x8*)(sE + (size_t)(e0 + base + lane) * 8);
        #pragma unroll
        for (int h = 0; h < 8; h++)
            pm[h] = fmaxf(pm[h], act ? (float)s8[h] : -1e30f);
    }
    float m[8];
    #pragma unroll
    for (int h = 0; h < 8; h++) {
        float v = pm[h];
        #pragma unroll
        for (int off = 1; off < 64; off <<= 1) v = fmaxf(v, __shfl_xor(v, off));
        m[h] = v;
    }
    // pass 2: P, V-MFMA, ones-MFMA (denominator)
    f32x4 acc0 = {}, acc1 = {}, accl = {};
    int ec0 = (lane >> 4) * 8, h_a = lane & 15, hsel = (lane >> 4) & 1;
    f16x8 ones;
    #pragma unroll
    for (int j = 0; j < 8; j++) ones[j] = (f16)1.f;
    for (int base = 0; base < deg; base += 64) {
        int nE = deg - base; if (nE > 64) nE = 64;
        bool act = lane < nE;
        int d = dstA[e0 + base + (act ? lane : 0)];
        dS[w][lane] = d;
        f16x8 s8 = {};
        if (act) s8 = *(const f16x8*)(sE + (size_t)(e0 + base + lane) * 8);
        #pragma unroll
        for (int h = 0; h < 8; h++) {
            float p = act ? __expf((float)s8[h] - m[h]) : 0.f;
            P_lds[w][h][lane ^ (h << 3)] = (f16)p;
        }
        // A-frags: P[h][k], k = ks*32 + ec0 + j (XOR-decoded contiguous b128)
        f16x8 a0 = *(const f16x8*)&P_lds[w][h_a][(ec0)      ^ ((h_a & 7) << 3)];
        f16x8 a1 = *(const f16x8*)&P_lds[w][h_a][(32 + ec0) ^ ((h_a & 7) << 3)];
        // B-frags: V[e][dim], dim = nh*16 + (lane&15)
        f16x8 bf0a, bf0b, bf1a, bf1b;
        #pragma unroll
        for (int j = 0; j < 8; j++) {
            int dd0 = dS[w][ec0 + j];
            int dd1 = dS[w][32 + ec0 + j];
            const f16* vp0 = Vb + (size_t)dd0 * 32 + (lane & 15);
            const f16* vp1 = Vb + (size_t)dd1 * 32 + (lane & 15);
            bf0a[j] = vp0[0];  bf0b[j] = vp0[16];
            bf1a[j] = vp1[0];  bf1b[j] = vp1[16];
        }
        acc0 = __builtin_amdgcn_mfma_f32_16x16x32_f16(a0, bf0a, acc0, 0, 0, 0);
        acc0 = __builtin_amdgcn_mfma_f32_16x16x32_f16(a1, bf1a, acc0, 0, 0, 0);
        acc1 = __builtin_amdgcn_mfma_f32_16x16x32_f16(a0, bf0b, acc1, 0, 0, 0);
        acc1 = __builtin_amdgcn_mfma_f32_16x16x32_f16(a1, bf1b, acc1, 0, 0, 0);
        accl = __builtin_amdgcn_mfma_f32_16x16x32_f16(a0, ones, accl, 0, 0, 0);
        accl = __builtin_amdgcn_mfma_f32_16x16x32_f16(a1, ones, accl, 0, 0, 0);
    }
    // epilogue: D row = hsel*4 + r = head, col = lane&15; out dim = h*32 + nh*16 + col
    if (lane < 32) {
        float* op = Out + (size_t)row * 256 + (lane & 15);
        #pragma unroll
        for (int r = 0; r < 4; r++) {
            int h = hsel * 4 + r;
            float inv = 1.f / accl[r];
            op[h * 32]      += acc0[r] * inv;
            op[h * 32 + 16] += acc1[r] * inv;
        }
    }
}

// ---------------- launch ----------------
extern "C" void kernel_launch(void* const* d_in, const int* in_sizes, int n_in,
                              void* d_out, int out_size, void* d_ws, size_t ws_size,
                              hipStream_t stream) {
    const float* F  = (const float*)d_in[0];
    const int*   ei = (const int*)d_in[1];
    const float* Wq = (const float*)d_in[2];
    const float* bq = (const float*)d_in[3];
    const float* Wk = (const float*)d_in[4];
    const float* bk = (const float*)d_in[5];
    const float* Ww = (const float*)d_in[6];
    const float* bw = (const float*)d_in[7];
    const float* Wb = (const float*)d_in[8];
    const float* bb = (const float*)d_in[9];
    int n = in_sizes[0] / 256;       // 50000
    int E = in_sizes[1] / 2;
    const int* srcA = ei;
    const int* dstA = ei + E;
    int n_pad = (n + 127) & ~127;

    // workspace carve-out (~133 MB); Fh and sE alias (Fh dead after gemm_fused)
    char* wp = (char*)d_ws;
    auto alloc = [&](size_t bytes) { void* p = wp; wp += (bytes + 255) & ~255ull; return p; };
    size_t fhB = (size_t)n_pad * 256 * 2;
    size_t seB = (size_t)E * 8 * 2;
    void*  reg0 = alloc(fhB > seB ? fhB : seB);
    f16*   Fh   = (f16*)reg0;
    f16*   sE   = (f16*)reg0;
    f16*   Wc   = (f16*)alloc((size_t)WC_PAD * 256 * 2);
    float* bias = (float*)alloc((size_t)WC_PAD * 4);
    f16*   Qb   = (f16*)alloc((size_t)n * 512 * 2);
    f16*   Kb   = (f16*)alloc((size_t)n * 512 * 2);
    f16*   Vb   = (f16*)alloc((size_t)n * 32 * 2);
    int*   rs   = (int*)alloc((size_t)(n + 1) * 4);
    float* Out  = (float*)d_out;

    prep_weights<<<WC_PAD, 256, 0, stream>>>(Wq, bq, Wk, bk, Ww, bw, Wb, bb, Wc, bias);
    long totalF = (long)n_pad * 256;
    conv_feat<<<(int)((totalF / 4 + 255) / 256), 256, 0, stream>>>(F, Fh, n, totalF);
    build_rows<<<(E + 255) / 256, 256, 0, stream>>>(srcA, E, n, rs);
    dim3 g(WC_PAD / 64, n_pad / 128);   // N fastest: A-panel L2-reuse, B L2-resident
    gemm_fused<<<g, 256, 0, stream>>>(Fh, Wc, bias, Qb, Kb, Vb, Out, n);
    long totalS = (long)E * 8;
    edge_scores<<<(int)((totalS + 255) / 256), 256, 0, stream>>>(srcA, dstA, Qb, Kb, sE, E);
    edge_agg<<<(n + 3) / 4, 256, 0, stream>>>(rs, dstA, sE, Vb, Out, n);
}

// Round 5
// 543.788 us; speedup vs baseline: 5.3754x; 1.0609x over previous
//
#include <hip/hip_runtime.h>
#include <hip/hip_fp16.h>

typedef _Float16 f16;
typedef _Float16 f16x2 __attribute__((ext_vector_type(2)));
typedef _Float16 f16x8 __attribute__((ext_vector_type(8)));
typedef float f32x4 __attribute__((ext_vector_type(4)));

// Combined projection: rows 0..511 = Wq (8 heads x 64), 512..1023 = Wk,
// 1024..1055 = Ww (V), 1056..1311 = Wb (output). Padded to 1344 rows.
#define WC_ROWS 1312
#define WC_PAD 1344

// ---------------- prep: combined weight matrix (f16) + bias (f32) ----------------
__global__ void prep_weights(const float* __restrict__ Wq, const float* __restrict__ bq,
                             const float* __restrict__ Wk, const float* __restrict__ bk,
                             const float* __restrict__ Ww, const float* __restrict__ bw,
                             const float* __restrict__ Wb, const float* __restrict__ bb,
                             f16* __restrict__ Wc, float* __restrict__ bias) {
    int id = blockIdx.x * 256 + threadIdx.x;   // WC_PAD*256 threads
    int j = id >> 8, k = id & 255;
    if (j >= WC_PAD) return;
    float v;
    if (j < 512)       v = Wq[j*256 + k];          // Wq flat [8,64,256]: row h*64+d == j
    else if (j < 1024) v = Wk[(j-512)*256 + k];
    else if (j < 1056) v = Ww[(j-1024)*256 + k];
    else if (j < 1312) v = Wb[(j-1056)*256 + k];
    else               v = 0.f;
    Wc[j*256 + k] = (f16)v;
    if (k == 0) {
        float b;
        if (j < 512)       b = bq[j];
        else if (j < 1024) b = bk[j-512];
        else if (j < 1056) b = bw[j-1024];
        else if (j < 1312) b = bb[j-1056];
        else               b = 0.f;
        bias[j] = b;
    }
}

// ---------------- prep: CSR row starts (edges sorted by src; every row non-empty) --
__global__ void build_rows(const int* __restrict__ src, int E, int n, int* __restrict__ rs) {
    int e = blockIdx.x * 256 + threadIdx.x;
    if (e == 0) rs[n] = E;
    if (e < E) {
        if (e == 0 || src[e] != src[e-1]) rs[src[e]] = e;
    }
}

// ---------------- fused projection GEMM (reads f32 features, converts inline) -----
// C[m][g] = sum_k F[m][k] * Wc[g][k] + bias[g];  scatter by g-region.
// Tile 128x64, BK=32, 4 waves (2x2), mfma_f32_16x16x32_f16.
__device__ __forceinline__ int swz_slot(int row, int c) {
    return row * 4 + (c ^ (row & 3) ^ ((row >> 2) & 3));
}

__device__ __forceinline__ uint4 cvt8(float4 a, float4 b) {
    f16x8 o;
    o[0] = (f16)a.x; o[1] = (f16)a.y; o[2] = (f16)a.z; o[3] = (f16)a.w;
    o[4] = (f16)b.x; o[5] = (f16)b.y; o[6] = (f16)b.z; o[7] = (f16)b.w;
    return __builtin_bit_cast(uint4, o);
}

__launch_bounds__(256)
__global__ void gemm_fused(const float* __restrict__ F, const f16* __restrict__ Wc,
                           const float* __restrict__ bias,
                           f16* __restrict__ Qb, f16* __restrict__ Kb, f16* __restrict__ Vb,
                           float* __restrict__ Out, int n) {
    __shared__ uint4 As4[512];   // 128 rows x 32 k (f16) = 8KB
    __shared__ uint4 Bs4[256];   // 64 rows x 32 k = 4KB
    int t = threadIdx.x;
    int lane = t & 63, w = t >> 6;
    int wm = w >> 1, wn = w & 1;
    long m0 = (long)blockIdx.y * 128;
    int n0 = blockIdx.x * 64;

    f32x4 acc[4][2];
    #pragma unroll
    for (int i = 0; i < 4; i++)
        #pragma unroll
        for (int j = 0; j < 2; j++)
            acc[i][j] = (f32x4){0.f, 0.f, 0.f, 0.f};

    int lrow = t >> 2, lc = t & 3;
    long row0 = m0 + lrow, row1 = m0 + 64 + lrow;
    const float4* Fg0 = (const float4*)(F + row0 * 256 + lc * 8);   // 8 f32 per thread
    const float4* Fg1 = (const float4*)(F + row1 * 256 + lc * 8);
    const uint4*  Bg  = (const uint4*)(Wc + (long)(n0 + lrow) * 256 + lc * 8);
    bool ok0 = row0 < n, ok1 = row1 < n;
    int ws0 = swz_slot(lrow, lc);
    int ws1 = swz_slot(lrow + 64, lc);
    int csw = (lane >> 4) ^ (lane & 3) ^ ((lane >> 2) & 3);
    int arow = wm * 64 + (lane & 15);
    int brow = wn * 32 + (lane & 15);

    float4 fa0 = {}, fb0 = {}, fa1 = {}, fb1 = {};
    if (ok0) { fa0 = Fg0[0]; fb0 = Fg0[1]; }
    if (ok1) { fa1 = Fg1[0]; fb1 = Fg1[1]; }
    uint4 rb = Bg[0];
    for (int kt = 0; kt < 8; ++kt) {
        if (kt) __syncthreads();
        As4[ws0] = cvt8(fa0, fb0);
        As4[ws1] = cvt8(fa1, fb1);
        Bs4[ws0] = rb;
        __syncthreads();
        if (kt < 7) {            // prefetch next K-slice (k step 32 f32 = 8 float4)
            if (ok0) { fa0 = Fg0[(kt + 1) * 8]; fb0 = Fg0[(kt + 1) * 8 + 1]; }
            if (ok1) { fa1 = Fg1[(kt + 1) * 8]; fb1 = Fg1[(kt + 1) * 8 + 1]; }
            rb  = Bg[(kt + 1) * 4];
        }
        f16x8 af[4], bf[2];
        const f16x8* Ap = (const f16x8*)As4;
        const f16x8* Bp = (const f16x8*)Bs4;
        #pragma unroll
        for (int i = 0; i < 4; i++) af[i] = Ap[(arow + i * 16) * 4 + csw];
        #pragma unroll
        for (int j = 0; j < 2; j++) bf[j] = Bp[(brow + j * 16) * 4 + csw];
        #pragma unroll
        for (int i = 0; i < 4; i++)
            #pragma unroll
            for (int j = 0; j < 2; j++)
                acc[i][j] = __builtin_amdgcn_mfma_f32_16x16x32_f16(af[i], bf[j], acc[i][j], 0, 0, 0);
    }

    #pragma unroll
    for (int i = 0; i < 4; i++) {
        long gmb = m0 + wm * 64 + i * 16 + (lane >> 4) * 4;
        #pragma unroll
        for (int j = 0; j < 2; j++) {
            int gn = n0 + wn * 32 + j * 16 + (lane & 15);
            float bv = bias[gn];
            #pragma unroll
            for (int r = 0; r < 4; r++) {
                long gm = gmb + r;
                if (gm >= n) continue;
                float v = acc[i][j][r] + bv;
                if (gn < 512)       Qb[gm * 512 + gn] = (f16)v;
                else if (gn < 1024) Kb[gm * 512 + (gn - 512)] = (f16)v;
                else if (gn < 1056) Vb[gm * 32 + (gn - 1024)] = (f16)v;
                else if (gn < 1312) Out[gm * 256 + (gn - 1056)] = v;
            }
        }
    }
}

// ---------------- f16x2 dot helper ----------------
__device__ __forceinline__ float fd2(unsigned a, unsigned b, float c) {
#if defined(__has_builtin)
#if __has_builtin(__builtin_amdgcn_fdot2)
    return __builtin_amdgcn_fdot2(__builtin_bit_cast(f16x2, a), __builtin_bit_cast(f16x2, b), c, false);
#else
    f16x2 x = __builtin_bit_cast(f16x2, a), y = __builtin_bit_cast(f16x2, b);
    return c + (float)x[0] * (float)y[0] + (float)x[1] * (float)y[1];
#endif
#else
    f16x2 x = __builtin_bit_cast(f16x2, a), y = __builtin_bit_cast(f16x2, b);
    return c + (float)x[0] * (float)y[0] + (float)x[1] * (float)y[1];
#endif
}

// ---------------- phase A: edge-parallel scores ----------------
// 8 lanes per edge (lane = head). All 16 loads issued into live registers BEFORE
// any use (v1's VGPR=32 allocation forced early waitcnts -> ~4-6 loads in flight).
// Bijective XCD swizzle (m204): each XCD gets a contiguous edge/src range so its
// Q slice (~6.4MB) stays L2-resident; K remains the fundamental random gather.
__launch_bounds__(256)
__global__ void edge_scores(const int* __restrict__ srcA, const int* __restrict__ dstA,
                            const f16* __restrict__ Qb, const f16* __restrict__ Kb,
                            f16* __restrict__ sE, int E, int nwg) {
    int bid = blockIdx.x;
    int q = nwg >> 3, r = nwg & 7, xcd = bid & 7, off = bid >> 3;
    int wg = (xcd < r ? xcd * (q + 1) : r * (q + 1) + (xcd - r) * q) + off;
    long id = (long)wg * 256 + threadIdx.x;
    int e = (int)(id >> 3), h = (int)(id & 7);
    if (e >= E) return;
    int s = srcA[e], d = dstA[e];
    const uint4* qp = (const uint4*)(Qb + (size_t)s * 512 + h * 64);
    const uint4* kp = (const uint4*)(Kb + (size_t)d * 512 + h * 64);
    uint4 kv[8], qv[8];
    #pragma unroll
    for (int c = 0; c < 8; c++) kv[c] = kp[c];   // random gather first (long latency)
    #pragma unroll
    for (int c = 0; c < 8; c++) qv[c] = qp[c];   // L2-hot stream
    float a0 = 0.f, a1 = 0.f;
    #pragma unroll
    for (int c = 0; c < 8; c += 2) {
        a0 = fd2(qv[c].x,   kv[c].x,   a0);
        a0 = fd2(qv[c].y,   kv[c].y,   a0);
        a0 = fd2(qv[c].z,   kv[c].z,   a0);
        a0 = fd2(qv[c].w,   kv[c].w,   a0);
        a1 = fd2(qv[c+1].x, kv[c+1].x, a1);
        a1 = fd2(qv[c+1].y, kv[c+1].y, a1);
        a1 = fd2(qv[c+1].z, kv[c+1].z, a1);
        a1 = fd2(qv[c+1].w, kv[c+1].w, a1);
    }
    sE[(size_t)e * 8 + h] = (f16)(a0 + a1);   // [e][h], coalesced 128B/wave
}

// ---------------- phase B: row-parallel softmax + MFMA aggregation ----------------
// Wave per row. Pass 1: per-head max. Pass 2: P = exp(s-m) -> LDS (XOR-swizzled);
// out[16h x 32d] = P @ Vgather via 4 MFMAs; denom l = P @ ones via 2 more MFMAs.
__launch_bounds__(256)
__global__ void edge_agg(const int* __restrict__ rs, const int* __restrict__ dstA,
                         const f16* __restrict__ sE, const f16* __restrict__ Vb,
                         float* __restrict__ Out, int n) {
    __shared__ __align__(16) f16 P_lds[4][16][64];
    __shared__ int dS[4][64];
    int w = threadIdx.x >> 6, lane = threadIdx.x & 63;
    int row = blockIdx.x * 4 + w;
    if (row >= n) return;
    int e0 = rs[row], deg = rs[row + 1] - e0;
    {   // zero A-frag rows 8..15 (read by MFMA, results discarded; avoid NaN garbage)
        f16x8 z = {};
        *(f16x8*)&P_lds[w][8 + (lane >> 3)][(lane & 7) * 8] = z;
    }
    // pass 1: global per-head max
    float pm[8];
    #pragma unroll
    for (int h = 0; h < 8; h++) pm[h] = -1e30f;
    for (int base = 0; base < deg; base += 64) {
        bool act = lane < deg - base;
        f16x8 s8 = {};
        if (act) s8 = *(const f16x8*)(sE + (size_t)(e0 + base + lane) * 8);
        #pragma unroll
        for (int h = 0; h < 8; h++)
            pm[h] = fmaxf(pm[h], act ? (float)s8[h] : -1e30f);
    }
    float m[8];
    #pragma unroll
    for (int h = 0; h < 8; h++) {
        float v = pm[h];
        #pragma unroll
        for (int off = 1; off < 64; off <<= 1) v = fmaxf(v, __shfl_xor(v, off));
        m[h] = v;
    }
    // pass 2: P, V-MFMA, ones-MFMA (denominator)
    f32x4 acc0 = {}, acc1 = {}, accl = {};
    int ec0 = (lane >> 4) * 8, h_a = lane & 15, hsel = (lane >> 4) & 1;
    f16x8 ones;
    #pragma unroll
    for (int j = 0; j < 8; j++) ones[j] = (f16)1.f;
    for (int base = 0; base < deg; base += 64) {
        int nE = deg - base; if (nE > 64) nE = 64;
        bool act = lane < nE;
        int d = dstA[e0 + base + (act ? lane : 0)];
        dS[w][lane] = d;
        f16x8 s8 = {};
        if (act) s8 = *(const f16x8*)(sE + (size_t)(e0 + base + lane) * 8);
        #pragma unroll
        for (int h = 0; h < 8; h++) {
            float p = act ? __expf((float)s8[h] - m[h]) : 0.f;
            P_lds[w][h][lane ^ (h << 3)] = (f16)p;
        }
        // A-frags: P[h][k], k = ks*32 + ec0 + j (XOR-decoded contiguous b128)
        f16x8 a0 = *(const f16x8*)&P_lds[w][h_a][(ec0)      ^ ((h_a & 7) << 3)];
        f16x8 a1 = *(const f16x8*)&P_lds[w][h_a][(32 + ec0) ^ ((h_a & 7) << 3)];
        // B-frags: V[e][dim], dim = nh*16 + (lane&15)
        f16x8 bf0a, bf0b, bf1a, bf1b;
        #pragma unroll
        for (int j = 0; j < 8; j++) {
            int dd0 = dS[w][ec0 + j];
            int dd1 = dS[w][32 + ec0 + j];
            const f16* vp0 = Vb + (size_t)dd0 * 32 + (lane & 15);
            const f16* vp1 = Vb + (size_t)dd1 * 32 + (lane & 15);
            bf0a[j] = vp0[0];  bf0b[j] = vp0[16];
            bf1a[j] = vp1[0];  bf1b[j] = vp1[16];
        }
        acc0 = __builtin_amdgcn_mfma_f32_16x16x32_f16(a0, bf0a, acc0, 0, 0, 0);
        acc0 = __builtin_amdgcn_mfma_f32_16x16x32_f16(a1, bf1a, acc0, 0, 0, 0);
        acc1 = __builtin_amdgcn_mfma_f32_16x16x32_f16(a0, bf0b, acc1, 0, 0, 0);
        acc1 = __builtin_amdgcn_mfma_f32_16x16x32_f16(a1, bf1b, acc1, 0, 0, 0);
        accl = __builtin_amdgcn_mfma_f32_16x16x32_f16(a0, ones, accl, 0, 0, 0);
        accl = __builtin_amdgcn_mfma_f32_16x16x32_f16(a1, ones, accl, 0, 0, 0);
    }
    // epilogue: D row = hsel*4 + r = head, col = lane&15; out dim = h*32 + nh*16 + col
    if (lane < 32) {
        float* op = Out + (size_t)row * 256 + (lane & 15);
        #pragma unroll
        for (int r = 0; r < 4; r++) {
            int h = hsel * 4 + r;
            float inv = 1.f / accl[r];
            op[h * 32]      += acc0[r] * inv;
            op[h * 32 + 16] += acc1[r] * inv;
        }
    }
}

// ---------------- launch ----------------
extern "C" void kernel_launch(void* const* d_in, const int* in_sizes, int n_in,
                              void* d_out, int out_size, void* d_ws, size_t ws_size,
                              hipStream_t stream) {
    const float* F  = (const float*)d_in[0];
    const int*   ei = (const int*)d_in[1];
    const float* Wq = (const float*)d_in[2];
    const float* bq = (const float*)d_in[3];
    const float* Wk = (const float*)d_in[4];
    const float* bk = (const float*)d_in[5];
    const float* Ww = (const float*)d_in[6];
    const float* bw = (const float*)d_in[7];
    const float* Wb = (const float*)d_in[8];
    const float* bb = (const float*)d_in[9];
    int n = in_sizes[0] / 256;       // 50000
    int E = in_sizes[1] / 2;
    const int* srcA = ei;
    const int* dstA = ei + E;
    int n_pad = (n + 127) & ~127;

    // workspace carve-out (~133 MB)
    char* wp = (char*)d_ws;
    auto alloc = [&](size_t bytes) { void* p = wp; wp += (bytes + 255) & ~255ull; return p; };
    f16*   sE   = (f16*)alloc((size_t)E * 8 * 2);
    f16*   Wc   = (f16*)alloc((size_t)WC_PAD * 256 * 2);
    float* bias = (float*)alloc((size_t)WC_PAD * 4);
    f16*   Qb   = (f16*)alloc((size_t)n * 512 * 2);
    f16*   Kb   = (f16*)alloc((size_t)n * 512 * 2);
    f16*   Vb   = (f16*)alloc((size_t)n * 32 * 2);
    int*   rs   = (int*)alloc((size_t)(n + 1) * 4);
    float* Out  = (float*)d_out;

    prep_weights<<<WC_PAD, 256, 0, stream>>>(Wq, bq, Wk, bk, Ww, bw, Wb, bb, Wc, bias);
    build_rows<<<(E + 255) / 256, 256, 0, stream>>>(srcA, E, n, rs);
    dim3 g(WC_PAD / 64, n_pad / 128);   // N fastest: A-panel L2-reuse, B L2-resident
    gemm_fused<<<g, 256, 0, stream>>>(F, Wc, bias, Qb, Kb, Vb, Out, n);
    int nwg = (int)(((long)E * 8 + 255) / 256);
    edge_scores<<<nwg, 256, 0, stream>>>(srcA, dstA, Qb, Kb, sE, E, nwg);
    edge_agg<<<(n + 3) / 4, 256, 0, stream>>>(rs, dstA, sE, Vb, Out, n);
}